// Round 2
// baseline (2405.306 us; speedup 1.0000x reference)
//
#include <hip/hip_runtime.h>
#include <hip/hip_bf16.h>

// Model_26439818674684: hierarchical LSTM forecaster.
// Key structural facts used:
//  - text LSTM layer 1 is DEAD (reference uses h0T only) -> skipped entirely.
//  - all recurrences are independent per sequence; input projections are
//    hoisted into big bf16 MFMA GEMMs (bias folded), recurrent h@Whh done
//    per-timestep with one kernel launch per step (round-1 simplicity).
// DIMS: DAYS=30 TOPICS=20 T=128 E=300 H=256 DH=64; batch text = 600.

typedef __attribute__((ext_vector_type(8))) short short8;
typedef __attribute__((ext_vector_type(8))) __bf16 bf16x8;
typedef __attribute__((ext_vector_type(4))) float f4;

static __device__ __forceinline__ short f2bf(float f){
  unsigned u = __builtin_bit_cast(unsigned, f);
  u = u + 0x7fffu + ((u >> 16) & 1u);
  return (short)(u >> 16);
}
static __device__ __forceinline__ float b2f(short s){
  unsigned u = ((unsigned)(unsigned short)s) << 16;
  return __builtin_bit_cast(float, u);
}
static __device__ __forceinline__ float sigm(float x){ return 1.f/(1.f + __expf(-x)); }
static __device__ __forceinline__ float tanh_f(float x){
  float e = __expf(-2.f*fabsf(x));
  float t = (1.f - e)/(1.f + e);
  return x < 0.f ? -t : t;
}
static __device__ __forceinline__ f4 mfma16(short8 a, short8 b, f4 c){
  return __builtin_amdgcn_mfma_f32_16x16x32_bf16(
      __builtin_bit_cast(bf16x8, a), __builtin_bit_cast(bf16x8, b), c, 0, 0, 0);
}

// ---------------- convert fp32 [N,K] -> bf16 [N,Kp] (zero-padded K) -------
__global__ void k_cvt_pad(const float* __restrict__ in, short* __restrict__ out,
                          int N, int K, int Kp){
  long total = (long)N * Kp;
  for (long i = (long)blockIdx.x*blockDim.x + threadIdx.x; i < total;
       i += (long)gridDim.x*blockDim.x){
    int k = (int)(i % Kp); long n = i / Kp;
    float v = (k < K) ? in[n*K + k] : 0.f;
    out[i] = f2bf(v);
  }
}

// ---------------- GEMM: C_bf16[M,N] = A[M,K] @ Bt[N,Kp]^T + bias[N] -------
// A is fp32 (stride Ka, Kp>=Ka padded logically) or bf16 (stride Kp exact).
// 128x128 tile, 4 waves, each wave 32 rows x 128 cols, 16x16x32 bf16 MFMA.
template<bool A_F32>
__global__ __launch_bounds__(256) void k_gemm(
    const void* __restrict__ Av, const short* __restrict__ Bt,
    const float* __restrict__ bias, short* __restrict__ C,
    int M, int N, int Kp, int Ka)
{
  int w = threadIdx.x >> 6, l = threadIdx.x & 63;
  int m0 = blockIdx.x*128 + w*32;
  int n0 = blockIdx.y*128;
  int lr = l & 15, lg = l >> 4;
  f4 acc[2][8];
  #pragma unroll
  for (int i=0;i<2;++i)
    #pragma unroll
    for (int j=0;j<8;++j) acc[i][j] = (f4){0.f,0.f,0.f,0.f};
  const float* Af = (const float*)Av;
  const short* Ab = (const short*)Av;
  int nkt = Kp >> 5;
  for (int kt = 0; kt < nkt; ++kt){
    int kb = kt*32 + lg*8;
    short8 a[2];
    #pragma unroll
    for (int mt = 0; mt < 2; ++mt){
      int m = m0 + mt*16 + lr;
      short8 av = {0,0,0,0,0,0,0,0};
      if (m < M){
        if (A_F32){
          if (kb + 7 < Ka){
            const float4* p4 = (const float4*)(Af + (long)m*Ka + kb);
            float4 x0 = p4[0], x1 = p4[1];
            av[0]=f2bf(x0.x); av[1]=f2bf(x0.y); av[2]=f2bf(x0.z); av[3]=f2bf(x0.w);
            av[4]=f2bf(x1.x); av[5]=f2bf(x1.y); av[6]=f2bf(x1.z); av[7]=f2bf(x1.w);
          } else {
            const float* p = Af + (long)m*Ka;
            #pragma unroll
            for (int j=0;j<8;++j) av[j] = (kb+j < Ka) ? f2bf(p[kb+j]) : (short)0;
          }
        } else {
          av = *(const short8*)(Ab + (long)m*Kp + kb);
        }
      }
      a[mt] = av;
    }
    #pragma unroll
    for (int nt = 0; nt < 8; ++nt){
      short8 b = *(const short8*)(Bt + (long)(n0 + nt*16 + lr)*Kp + kb);
      acc[0][nt] = mfma16(a[0], b, acc[0][nt]);
      acc[1][nt] = mfma16(a[1], b, acc[1][nt]);
    }
  }
  #pragma unroll
  for (int nt = 0; nt < 8; ++nt){
    int col = n0 + nt*16 + lr;
    float bv = bias ? bias[col] : 0.f;
    #pragma unroll
    for (int mt = 0; mt < 2; ++mt){
      #pragma unroll
      for (int r = 0; r < 4; ++r){
        int row = m0 + mt*16 + lg*4 + r;
        if (row < M) C[(long)row*N + col] = f2bf(acc[mt][nt][r] + bv);
      }
    }
  }
}

// ---------------- one LSTM timestep (per-step launch) ---------------------
// Block = [32 seqs x 32 hidden-units] (=128 gate cols: wave w owns gate w).
// gates = G[s*T+t, :] (precomputed inproj+bias, bf16) + h_bf @ Whh^T (MFMA).
__global__ __launch_bounds__(256) void k_lstm_step(
    const short* __restrict__ G,     // [nseq*T, 1024]
    const short* __restrict__ Whh,   // [1024, 256] bf16
    short* __restrict__ h_bf,        // [nseq, 256]
    float* __restrict__ c,           // [nseq, 256]
    short* __restrict__ y_bf,        // optional [nseq*T, 256]
    float* __restrict__ y_f32,       // optional [nseq*T, 256]
    float* __restrict__ h_f32,       // optional [nseq, 256]
    int nseq, int T, int t)
{
  __shared__ float gbuf[4*32*36];
  int w = threadIdx.x >> 6, l = threadIdx.x & 63;
  int s0 = blockIdx.x * 32;
  int u0 = blockIdx.y * 32;
  int lr = l & 15, lg = l >> 4;
  f4 acc[2][2];
  #pragma unroll
  for (int i=0;i<2;++i){ acc[i][0]=(f4){0,0,0,0}; acc[i][1]=(f4){0,0,0,0}; }
  if (t > 0){
    for (int kt = 0; kt < 8; ++kt){
      int kb = kt*32 + lg*8;
      short8 a[2];
      #pragma unroll
      for (int mt=0; mt<2; ++mt){
        int s = s0 + mt*16 + lr;
        short8 av = {0,0,0,0,0,0,0,0};
        if (s < nseq) av = *(const short8*)(h_bf + (long)s*256 + kb);
        a[mt] = av;
      }
      #pragma unroll
      for (int ntl=0; ntl<2; ++ntl){
        int row = w*256 + u0 + ntl*16 + lr;   // gate w, unit u0+ntl*16+lr
        short8 b = *(const short8*)(Whh + (long)row*256 + kb);
        acc[0][ntl] = mfma16(a[0], b, acc[0][ntl]);
        acc[1][ntl] = mfma16(a[1], b, acc[1][ntl]);
      }
    }
  }
  // add precomputed inproj and stage gates to LDS (gbuf[gate][m][unit])
  #pragma unroll
  for (int ntl=0; ntl<2; ++ntl){
    int ur = ntl*16 + lr;
    int coln = w*256 + u0 + ur;
    #pragma unroll
    for (int mt=0; mt<2; ++mt){
      #pragma unroll
      for (int r=0;r<4;++r){
        int m = mt*16 + lg*4 + r;
        int s = s0 + m;
        float gv = acc[mt][ntl][r];
        if (s < nseq) gv += b2f(G[(long)(s*T + t)*1024 + coln]);
        gbuf[(w*32 + m)*36 + ur] = gv;
      }
    }
  }
  __syncthreads();
  for (int i = 0; i < 4; ++i){
    int idx = i*256 + threadIdx.x;
    int m = idx >> 5, ur = idx & 31;
    int s = s0 + m, u = u0 + ur;
    if (s >= nseq) continue;
    float gi = gbuf[(0*32+m)*36+ur];
    float gf = gbuf[(1*32+m)*36+ur];
    float gg = gbuf[(2*32+m)*36+ur];
    float go = gbuf[(3*32+m)*36+ur];
    float cold = (t>0) ? c[(long)s*256+u] : 0.f;
    float cn = sigm(gf)*cold + sigm(gi)*tanh_f(gg);
    float hn = sigm(go)*tanh_f(cn);
    c[(long)s*256+u] = cn;
    short hb = f2bf(hn);
    h_bf[(long)s*256+u] = hb;
    if (y_bf)  y_bf[(long)(s*T+t)*256 + u] = hb;
    if (y_f32) y_f32[(long)(s*T+t)*256 + u] = hn;
    if (h_f32) h_f32[(long)s*256+u] = hn;
  }
}

// ---------------- day LSTM (batch=1, hidden 64, gates 256), 1 block ------
__global__ __launch_bounds__(1024) void k_day_lstm(
    const short* __restrict__ Gd,   // [T,256] bf16 (inproj+bias)
    const float* __restrict__ Whh,  // [256,64] fp32
    short* __restrict__ y_bf,       // optional [T,64]
    float* __restrict__ y_f32,      // optional [T,64]
    float* __restrict__ hT_f32,     // optional [64]
    int T)
{
  __shared__ float whhT[64*257];    // transposed, padded stride 257
  __shared__ float h[64], cc[64], part[4][256], gates[256];
  int tid = threadIdx.x;
  for (int i = tid; i < 256*64; i += 1024){
    int n = i >> 6, k = i & 63;
    whhT[k*257 + n] = Whh[i];
  }
  if (tid < 64){ h[tid]=0.f; cc[tid]=0.f; }
  __syncthreads();
  int n = tid & 255, kg = tid >> 8;
  for (int t = 0; t < T; ++t){
    float p = 0.f;
    #pragma unroll
    for (int kk = 0; kk < 16; ++kk){
      int k = kg*16 + kk;
      p += h[k]*whhT[k*257+n];
    }
    part[kg][n] = p;
    __syncthreads();
    if (tid < 256)
      gates[tid] = b2f(Gd[t*256+tid]) + part[0][tid]+part[1][tid]+part[2][tid]+part[3][tid];
    __syncthreads();
    if (tid < 64){
      float gi=gates[tid], gf=gates[64+tid], gg=gates[128+tid], go=gates[192+tid];
      float cn = sigm(gf)*cc[tid] + sigm(gi)*tanh_f(gg);
      float hn = sigm(go)*tanh_f(cn);
      cc[tid]=cn; h[tid]=hn;
      if (y_bf)  y_bf[t*64+tid]  = f2bf(hn);
      if (y_f32) y_f32[t*64+tid] = hn;
      if (hT_f32 && t==T-1) hT_f32[tid] = hn;
    }
    __syncthreads();
  }
}

// ---------------- per-day topic attention (truncated top-p 0.8) ----------
__global__ __launch_bounds__(256) void k_topic_attn(
    const float* __restrict__ y1,   // [30*20,256] topic L1 outputs
    const float* __restrict__ hT,   // [30,256]    topic L0 final hidden
    const float* __restrict__ w1W, const float* __restrict__ w1b,
    short* __restrict__ dayh)       // [30,256] bf16
{
  int d = blockIdx.x, tid = threadIdx.x;
  __shared__ float hf[256], red[4], sc[20], wk[20], c0s;
  hf[tid] = hT[d*256+tid];
  __syncthreads();
  float v = 0.f;
  for (int j=0;j<256;++j) v += hf[j]*w1W[j*256+tid];   // v = w1^T hf (per col)
  float p0 = w1b[tid]*hf[tid];
  #pragma unroll
  for (int o=32;o>0;o>>=1) p0 += __shfl_down(p0,o);
  if ((tid&63)==0) red[tid>>6] = p0;
  __syncthreads();
  if (tid==0) c0s = red[0]+red[1]+red[2]+red[3];
  __syncthreads();
  for (int t=0;t<20;++t){
    float p = y1[(d*20+t)*256+tid]*v;
    #pragma unroll
    for (int o=32;o>0;o>>=1) p += __shfl_down(p,o);
    if ((tid&63)==0) red[tid>>6] = p;
    __syncthreads();
    if (tid==0) sc[t] = red[0]+red[1]+red[2]+red[3] + c0s;
    __syncthreads();
  }
  if (tid==0){
    float mx = -1e30f;
    for (int t=0;t<20;++t) mx = fmaxf(mx, sc[t]);
    float ss = 0.f;
    for (int t=0;t<20;++t){ sc[t] = __expf(sc[t]-mx); ss += sc[t]; }
    float inv = 1.f/ss;
    for (int t=0;t<20;++t) sc[t] *= inv;
    for (int t=0;t<20;++t){
      float pref = 0.f;
      for (int q=0;q<20;++q)
        if (sc[q]>sc[t] || (sc[q]==sc[t] && q<t)) pref += sc[q];  // exclusive prefix in sorted order
      wk[t] = (pref <= 0.8f) ? sc[t] : 0.f;
    }
  }
  __syncthreads();
  float a = 0.f;
  for (int t=0;t<20;++t) a += wk[t]*y1[(d*20+t)*256+tid];
  dayh[d*256+tid] = f2bf(a);
}

// ---------------- final: day attention + linears + head ------------------
__global__ __launch_bounds__(64) void k_final(
    const float* __restrict__ y1,  // [30,64] day L1 outputs
    const float* __restrict__ hT,  // [64]    day L0 final hidden
    const float* __restrict__ w2W, const float* __restrict__ w2b,
    const float* __restrict__ l1W, const float* __restrict__ l1b,
    const float* __restrict__ l2W, const float* __restrict__ l2b,
    const float* __restrict__ hW,  const float* __restrict__ hb,
    const float* __restrict__ prev, float* __restrict__ out)
{
  int tid = threadIdx.x;
  __shared__ float hf[64], v2[64], sc[30], ctx[64], h1[48], h2[16], c0s;
  hf[tid] = hT[tid];
  __syncthreads();
  { float v=0.f; for (int j=0;j<64;++j) v += hf[j]*w2W[j*64+tid]; v2[tid]=v; }
  if (tid==0){ float c0=0.f; for (int j=0;j<64;++j) c0 += w2b[j]*hf[j]; c0s=c0; }
  __syncthreads();
  if (tid<30){ float s=c0s; for (int k=0;k<64;++k) s += y1[tid*64+k]*v2[k]; sc[tid]=s; }
  __syncthreads();
  if (tid==0){
    float mx=-1e30f; for (int d=0;d<30;++d) mx=fmaxf(mx,sc[d]);
    float ss=0.f; for (int d=0;d<30;++d){ sc[d]=__expf(sc[d]-mx); ss+=sc[d]; }
    float inv=1.f/ss; for (int d=0;d<30;++d) sc[d]*=inv;
  }
  __syncthreads();
  { float cx=0.f; for (int d=0;d<30;++d) cx += sc[d]*y1[d*64+tid]; ctx[tid]=cx; }
  __syncthreads();
  if (tid<48){ float s=l1b[tid]; for (int k=0;k<64;++k) s += ctx[k]*l1W[tid*64+k]; h1[tid]=s; }
  __syncthreads();
  if (tid<16){ float s=l2b[tid]; for (int k=0;k<48;++k) s += h1[k]*l2W[tid*48+k]; h2[tid]=s; }
  __syncthreads();
  if (tid<4){
    float s = hb[tid];
    for (int cI=0;cI<16;++cI) s += h2[cI]*hW[tid*20+cI];
    for (int cI=0;cI<4; ++cI) s += prev[tid*4+cI]*hW[tid*20+16+cI];
    out[tid] = s;
  }
}

// ========================================================================
extern "C" void kernel_launch(void* const* d_in, const int* in_sizes, int n_in,
                              void* d_out, int out_size, void* d_ws, size_t ws_size,
                              hipStream_t stream)
{
  const float* X        = (const float*)d_in[0];   // [30,20,128,300]
  const float* prev     = (const float*)d_in[1];   // [4,4]
  const float* tWih0    = (const float*)d_in[2];   // [1024,300]
  const float* tWhh0    = (const float*)d_in[3];   // [1024,256]
  const float* tb0      = (const float*)d_in[4];   // [1024]
  // d_in[5..7] text layer-1: DEAD (reference discards text layer-1 output)
  const float* pWih0    = (const float*)d_in[8];
  const float* pWhh0    = (const float*)d_in[9];
  const float* pb0      = (const float*)d_in[10];
  const float* pWih1    = (const float*)d_in[11];
  const float* pWhh1    = (const float*)d_in[12];
  const float* pb1      = (const float*)d_in[13];
  const float* dWih0    = (const float*)d_in[14];  // [256,256]
  const float* dWhh0    = (const float*)d_in[15];  // [256,64]
  const float* db0      = (const float*)d_in[16];
  const float* dWih1    = (const float*)d_in[17];  // [256,64]
  const float* dWhh1    = (const float*)d_in[18];  // [256,64]
  const float* db1      = (const float*)d_in[19];
  const float* w1W      = (const float*)d_in[20];
  const float* w1b      = (const float*)d_in[21];
  const float* w2W      = (const float*)d_in[22];
  const float* w2b      = (const float*)d_in[23];
  const float* l1W      = (const float*)d_in[24];
  const float* l1b      = (const float*)d_in[25];
  const float* l2W      = (const float*)d_in[26];
  const float* l2b      = (const float*)d_in[27];
  const float* hW       = (const float*)d_in[28];
  const float* hb       = (const float*)d_in[29];
  float* out = (float*)d_out;

  char* wsb = (char*)d_ws;
  size_t off = 0;
  auto alloc = [&](size_t bytes)->void*{
    void* p = wsb + off;
    off = (off + bytes + 255) & ~(size_t)255;
    return p;
  };
  short* G0      = (short*)alloc((size_t)76800*1024*2);
  short* WihT    = (short*)alloc((size_t)1024*320*2);
  short* Whh0b   = (short*)alloc((size_t)1024*256*2);
  short* pW0i    = (short*)alloc((size_t)1024*256*2);
  short* pW0h    = (short*)alloc((size_t)1024*256*2);
  short* pW1i    = (short*)alloc((size_t)1024*256*2);
  short* pW1h    = (short*)alloc((size_t)1024*256*2);
  short* dW0i    = (short*)alloc((size_t)256*256*2);
  short* dW1i    = (short*)alloc((size_t)256*64*2);
  short* h_text  = (short*)alloc((size_t)600*256*2);
  float* c_text  = (float*)alloc((size_t)600*256*4);
  short* Gt0     = (short*)alloc((size_t)600*1024*2);
  short* h_t0    = (short*)alloc((size_t)30*256*2);
  float* c_t0    = (float*)alloc((size_t)30*256*4);
  short* y_t0    = (short*)alloc((size_t)600*256*2);
  float* h_topf  = (float*)alloc((size_t)30*256*4);
  short* Gt1     = (short*)alloc((size_t)600*1024*2);
  short* h_t1    = (short*)alloc((size_t)30*256*2);
  float* c_t1    = (float*)alloc((size_t)30*256*4);
  float* y_t1f   = (float*)alloc((size_t)600*256*4);
  short* dayh    = (short*)alloc((size_t)30*256*2);
  short* Gd0     = (short*)alloc((size_t)30*256*2);
  short* y_d0    = (short*)alloc((size_t)30*64*2);
  float* h_d0f   = (float*)alloc((size_t)64*4);
  short* Gd1     = (short*)alloc((size_t)30*256*2);
  float* y_d1f   = (float*)alloc((size_t)30*64*4);
  (void)ws_size; (void)in_sizes; (void)n_in; (void)out_size;

  // --- weight conversions to bf16 (B^T layout, zero-padded K) ---
  k_cvt_pad<<<512,256,0,stream>>>(tWih0, WihT, 1024, 300, 320);
  k_cvt_pad<<<512,256,0,stream>>>(tWhh0, Whh0b, 1024, 256, 256);
  k_cvt_pad<<<512,256,0,stream>>>(pWih0, pW0i, 1024, 256, 256);
  k_cvt_pad<<<512,256,0,stream>>>(pWhh0, pW0h, 1024, 256, 256);
  k_cvt_pad<<<512,256,0,stream>>>(pWih1, pW1i, 1024, 256, 256);
  k_cvt_pad<<<512,256,0,stream>>>(pWhh1, pW1h, 1024, 256, 256);
  k_cvt_pad<<<256,256,0,stream>>>(dWih0, dW0i, 256, 256, 256);
  k_cvt_pad<<<64,256,0,stream>>>(dWih1, dW1i, 256, 64, 64);

  // --- text layer-0 input projection: [76800,300]@[300,1024]+b ---
  k_gemm<true><<<dim3(600,8),256,0,stream>>>((const void*)X, WihT, tb0, G0,
                                             76800, 1024, 320, 300);
  // --- text layer-0 recurrence: 128 steps, 600 independent sequences ---
  for (int t = 0; t < 128; ++t)
    k_lstm_step<<<dim3(19,8),256,0,stream>>>(G0, Whh0b, h_text, c_text,
                                             nullptr, nullptr, nullptr, 600, 128, t);
  // h_text (bf16, rows = day*20+topic) == topic LSTM input rows. L0 inproj:
  k_gemm<false><<<dim3(5,8),256,0,stream>>>((const void*)h_text, pW0i, pb0, Gt0,
                                            600, 1024, 256, 256);
  for (int t = 0; t < 20; ++t)
    k_lstm_step<<<dim3(1,8),256,0,stream>>>(Gt0, pW0h, h_t0, c_t0,
                                            y_t0, nullptr, h_topf, 30, 20, t);
  k_gemm<false><<<dim3(5,8),256,0,stream>>>((const void*)y_t0, pW1i, pb1, Gt1,
                                            600, 1024, 256, 256);
  for (int t = 0; t < 20; ++t)
    k_lstm_step<<<dim3(1,8),256,0,stream>>>(Gt1, pW1h, h_t1, c_t1,
                                            nullptr, y_t1f, nullptr, 30, 20, t);
  // --- per-day topic attention -> day_hidden [30,256] bf16 ---
  k_topic_attn<<<30,256,0,stream>>>(y_t1f, h_topf, w1W, w1b, dayh);
  // --- day LSTM (batch=1) ---
  k_gemm<false><<<dim3(1,2),256,0,stream>>>((const void*)dayh, dW0i, db0, Gd0,
                                            30, 256, 256, 256);
  k_day_lstm<<<1,1024,0,stream>>>(Gd0, dWhh0, y_d0, nullptr, h_d0f, 30);
  k_gemm<false><<<dim3(1,2),256,0,stream>>>((const void*)y_d0, dW1i, db1, Gd1,
                                            30, 256, 64, 64);
  k_day_lstm<<<1,1024,0,stream>>>(Gd1, dWhh1, nullptr, y_d1f, nullptr, 30);
  // --- day attention + linears + head -> out[4] ---
  k_final<<<1,64,0,stream>>>(y_d1f, h_d0f, w2W, w2b, l1W, l1b, l2W, l2b,
                             hW, hb, prev, out);
}